// Round 8
// baseline (200.764 us; speedup 1.0000x reference)
//
#include <hip/hip_runtime.h>
#include <stdint.h>
#include <math.h>

// Problem constants
#define NN 8192     // graph nodes == GEMM K
#define HD 256      // hidden dim == GEMM N
#define BATCH 2048
#define KSPLIT 8
#define KCH (NN / KSPLIT)   // 1024 K per kblk
#define NBLK 512            // grid size; 2 blocks/CU co-resident (capacity barrier)

typedef __attribute__((ext_vector_type(8))) short bf16x8;
typedef __attribute__((ext_vector_type(4))) float f32x4;

static __device__ __forceinline__ uint32_t pack_bf2(float x, float y) {
  union { float f; uint32_t u; } a, b; a.f = x; b.f = y;
  uint32_t ua = a.u + 0x7FFFu + ((a.u >> 16) & 1u);
  uint32_t ub = b.u + 0x7FFFu + ((b.u >> 16) & 1u);
  return (ua >> 16) | (ub & 0xFFFF0000u);
}
static __device__ __forceinline__ float bf_lo(uint32_t u) {
  return __uint_as_float(u << 16);
}
static __device__ __forceinline__ float bf_hi(uint32_t u) {
  return __uint_as_float(u & 0xFFFF0000u);
}

// device-scope counting barrier; all NBLK blocks are co-resident by capacity
// (__launch_bounds__(256,2): 2 blocks/CU x 256 CUs = 512). ACQ_REL atomics
// give cross-XCD release/acquire (L2 writeback + invalidate).
static __device__ __forceinline__ void grid_barrier(uint32_t* cnt, int idx) {
  __syncthreads();
  if (threadIdx.x == 0) {
    __threadfence();
    __hip_atomic_fetch_add(&cnt[idx * 32], 1u, __ATOMIC_ACQ_REL,
                           __HIP_MEMORY_SCOPE_AGENT);
    while (__hip_atomic_load(&cnt[idx * 32], __ATOMIC_ACQUIRE,
                             __HIP_MEMORY_SCOPE_AGENT) < (uint32_t)NBLK) {
      __builtin_amdgcn_s_sleep(8);
    }
    __threadfence();
  }
  __syncthreads();
}

// ================================================================ fused:
// phase A: prep Bm (frag-major bf16 of emb^T, XCD-local) + Wm (conv weights)
// phase B: split-K gather-GEMM  Rp[kblk][4096][256] bf16   (r6 body verbatim)
// phase C: reduce partials -> t -> tiny MFMA vs Wm -> log-softmax out
extern "C" __global__ __launch_bounds__(256, 2)
void k_all(const float* __restrict__ emb, const float* __restrict__ A,
           const float* __restrict__ k1, const float* __restrict__ k2,
           const float* __restrict__ b1, const float* __restrict__ b2,
           const float* __restrict__ dw, const float* __restrict__ dbias,
           const int* __restrict__ bx, const int* __restrict__ by,
           float* __restrict__ out,
           uint16_t* __restrict__ Bm, uint16_t* __restrict__ Wm,
           uint16_t* __restrict__ Rp, uint32_t* __restrict__ cnt) {
  __shared__ __align__(16) char smem[33024];
  const int tid = threadIdx.x;
  const int bid = blockIdx.x;

  // ======================= phase A: prep =======================
  if (bid < 256) {
    // kc chosen so this XCD (bid%8) produces the B-slice it will consume
    const int kc = (bid & 7) * 32 + (bid >> 3);
    float (*ts)[257] = (float(*)[257])smem;
#pragma unroll
    for (int i = 0; i < 32; i++)
      ts[i][tid] = emb[(size_t)(kc * 32 + i) * HD + tid];
    __syncthreads();
#pragma unroll
    for (int c = 0; c < 4; c++) {
      int e = c * 256 + tid;
      int ci = e >> 6, l = e & 63;
      int g = l >> 4, col = ci * 16 + (l & 15);
      uint4 v;
      v.x = pack_bf2(ts[g * 8 + 0][col], ts[g * 8 + 1][col]);
      v.y = pack_bf2(ts[g * 8 + 2][col], ts[g * 8 + 3][col]);
      v.z = pack_bf2(ts[g * 8 + 4][col], ts[g * 8 + 5][col]);
      v.w = pack_bf2(ts[g * 8 + 6][col], ts[g * 8 + 7][col]);
      ((uint4*)Bm)[(size_t)kc * 1024 + e] = v;
    }
  } else if (bid < 352) {
    const int c = (bid - 256) * 256 + tid;   // 0..24575
    const int lcl = c & 63;
    const int ci = (c >> 6) % 24;
    const int kc = c / (24 * 64);
    const int j = ci * 16 + (lcl & 15);
    const int k0 = kc * 32 + ((lcl >> 4) << 3);
    float f[8];
#pragma unroll
    for (int jj = 0; jj < 8; jj++) {
      int k = k0 + jj;
      f[jj] = (j < 128) ? k1[j * 514 + 1 + k]
            : (j < 256) ? k2[(j - 128) * 1028 + 515 + k]
                        : k2[(j - 256) * 1028 + 1 + k];
    }
    uint4 v;
    v.x = pack_bf2(f[0], f[1]); v.y = pack_bf2(f[2], f[3]);
    v.z = pack_bf2(f[4], f[5]); v.w = pack_bf2(f[6], f[7]);
    *(uint4*)(Wm + (size_t)c * 8) = v;
  }
  grid_barrier(cnt, 0);

  // ======================= phase B: gemm =======================
  {
    uint16_t* shb = (uint16_t*)smem;               // Af[2][4096] | Ct[64][256]
    const int kblk = bid & 7;                      // XCD = bid%8 == kblk
    const int mblk = bid >> 3;
    const int wv = tid >> 6, l = tid & 63, g = l >> 4, l15 = l & 15;

    // A gather: row = tid>>2 (4 threads per row, 16B each, contiguous)
    const int row = tid >> 2, q = tid & 3;
    const int gr = mblk * 64 + row;
    const int arow = (gr < BATCH) ? bx[gr] : by[gr - BATCH];
    const float* aSrc = A + (size_t)arow * NN + kblk * KCH + q * 4;
    int ldsO[4];
#pragma unroll
    for (int ii = 0; ii < 4; ii++) {
      int k0 = q * 4 + 16 * ii;
      int chunk = ((k0 >> 5) * 4 + (row >> 4)) * 64 + ((k0 >> 3) & 3) * 16 + (row & 15);
      ldsO[ii] = chunk * 16 + (k0 & 7) * 2;
    }
    const int ldsO0 = ldsO[0], ldsO1 = ldsO[1], ldsO2 = ldsO[2], ldsO3 = ldsO[3];
    const uint16_t* bWave = Bm + ((size_t)(kblk * 32 * 16 + wv * 4) * 64 + l) * 8;

    f32x4 acc[4][4] = {};
    float4 a0a, a0b, a0c, a0d, a1a, a1b, a1c, a1d, a2a, a2b, a2c, a2d;
    bf16x8 b0[2][4], b1[2][4];

#define ISSUE_A0(i) { const float* p_ = aSrc + (i) * 64; \
    a0a = *(const float4*)(p_);      a0b = *(const float4*)(p_ + 16); \
    a0c = *(const float4*)(p_ + 32); a0d = *(const float4*)(p_ + 48); }
#define ISSUE_A1(i) { const float* p_ = aSrc + (i) * 64; \
    a1a = *(const float4*)(p_);      a1b = *(const float4*)(p_ + 16); \
    a1c = *(const float4*)(p_ + 32); a1d = *(const float4*)(p_ + 48); }
#define ISSUE_A2(i) { const float* p_ = aSrc + (i) * 64; \
    a2a = *(const float4*)(p_);      a2b = *(const float4*)(p_ + 16); \
    a2c = *(const float4*)(p_ + 32); a2d = *(const float4*)(p_ + 48); }
#define ISSUE_B0(i) { \
    _Pragma("unroll") for (int kk = 0; kk < 2; kk++) \
    _Pragma("unroll") for (int cj = 0; cj < 4; cj++) \
      b0[kk][cj] = *(const bf16x8*)(bWave + ((i) * 2 + kk) * 8192 + cj * 512); }
#define ISSUE_B1(i) { \
    _Pragma("unroll") for (int kk = 0; kk < 2; kk++) \
    _Pragma("unroll") for (int cj = 0; cj < 4; cj++) \
      b1[kk][cj] = *(const bf16x8*)(bWave + ((i) * 2 + kk) * 8192 + cj * 512); }
#define PK1(va, off, buf) { uint2 v_; \
    v_.x = pack_bf2(va.x, va.y); v_.y = pack_bf2(va.z, va.w); \
    *(uint2*)((char*)shb + (buf) * 8192 + (off)) = v_; }
#define PACK_A0(buf) { PK1(a0a, ldsO0, buf); PK1(a0b, ldsO1, buf); \
                       PK1(a0c, ldsO2, buf); PK1(a0d, ldsO3, buf); }
#define PACK_A1(buf) { PK1(a1a, ldsO0, buf); PK1(a1b, ldsO1, buf); \
                       PK1(a1c, ldsO2, buf); PK1(a1d, ldsO3, buf); }
#define PACK_A2(buf) { PK1(a2a, ldsO0, buf); PK1(a2b, ldsO1, buf); \
                       PK1(a2c, ldsO2, buf); PK1(a2d, ldsO3, buf); }
#define COMPUTE(buf, bs) { \
    _Pragma("unroll") for (int kk = 0; kk < 2; kk++) { \
      _Pragma("unroll") for (int ri = 0; ri < 4; ri++) { \
        bf16x8 af = *(const bf16x8*)((char*)shb + (buf) * 8192 + \
                                     ((kk * 4 + ri) * 64 + l) * 16); \
        _Pragma("unroll") for (int cj = 0; cj < 4; cj++) \
          acc[ri][cj] = __builtin_amdgcn_mfma_f32_16x16x32_bf16( \
              af, bs[kk][cj], acc[ri][cj], 0, 0, 0); } } }
#define SYNC_ { asm volatile("s_waitcnt lgkmcnt(0)" ::: "memory"); \
    __builtin_amdgcn_s_barrier(); asm volatile("" ::: "memory"); }

    ISSUE_A0(0); ISSUE_A1(1); ISSUE_A2(2);
    ISSUE_B0(0); ISSUE_B1(1);
    PACK_A0(0);
    SYNC_;

#define SIX(base) \
  { COMPUTE(0, b0); ISSUE_A0((base) + 3); ISSUE_B0((base) + 2); PACK_A1(1); SYNC_; } \
  { COMPUTE(1, b1); ISSUE_A1((base) + 4); ISSUE_B1((base) + 3); PACK_A2(0); SYNC_; } \
  { COMPUTE(0, b0); ISSUE_A2((base) + 5); ISSUE_B0((base) + 4); PACK_A0(1); SYNC_; } \
  { COMPUTE(1, b1); ISSUE_A0((base) + 6); ISSUE_B1((base) + 5); PACK_A1(0); SYNC_; } \
  { COMPUTE(0, b0); ISSUE_A1((base) + 7); ISSUE_B0((base) + 6); PACK_A2(1); SYNC_; } \
  { COMPUTE(1, b1); ISSUE_A2((base) + 8); ISSUE_B1((base) + 7); PACK_A0(0); SYNC_; }

    SIX(0);
    SIX(6);
    { COMPUTE(0, b0); ISSUE_A0(15); ISSUE_B0(14); PACK_A1(1); SYNC_; }
    { COMPUTE(1, b1); ISSUE_B1(15); PACK_A2(0); SYNC_; }
    { COMPUTE(0, b0); PACK_A0(1); SYNC_; }
    { COMPUTE(1, b1); }
    SYNC_;                      // all LDS reads done; shb reusable as Ct

    uint16_t* Ct = shb;
#pragma unroll
    for (int ri = 0; ri < 4; ri++)
#pragma unroll
      for (int cj = 0; cj < 4; cj++)
#pragma unroll
        for (int r = 0; r < 4; r++) {
          float v = acc[ri][cj][r];
          float vn = __shfl_xor(v, 1);
          if ((l15 & 1) == 0) {
            int row16 = ri * 16 + g * 4 + r;
            int col = wv * 64 + cj * 16 + l15;
            *(uint32_t*)(Ct + row16 * 256 + col) = pack_bf2(v, vn);
          }
        }
    __syncthreads();
    {
      const int row2 = tid >> 2, cb = (tid & 3) * 64;
      const uint4* src = (const uint4*)(Ct + row2 * 256 + cb);
      uint16_t* dst = Rp + ((size_t)kblk * 4096 + mblk * 64 + row2) * HD + cb;
      uint4 v0 = src[0], v1 = src[1], v2 = src[2], v3 = src[3];
      ((uint4*)dst)[0] = v0; ((uint4*)dst)[1] = v1;
      ((uint4*)dst)[2] = v2; ((uint4*)dst)[3] = v3;
    }
#undef ISSUE_A0
#undef ISSUE_A1
#undef ISSUE_A2
#undef ISSUE_B0
#undef ISSUE_B1
#undef PK1
#undef PACK_A0
#undef PACK_A1
#undef PACK_A2
#undef COMPUTE
#undef SYNC_
#undef SIX
  }
  grid_barrier(cnt, 1);

  // ======================= phase C: tail =======================
  {
    uint16_t* t_frag = (uint16_t*)smem;                       // 16 KB
    float (*Cl)[388] = (float(*)[388])(smem + 16384);         // 4 rows used
    float (*coef)[128] = (float(*)[128])(smem + 22592);       // 3 KB
    const int b0 = bid * 4;
    const int wv = tid >> 6, l = tid & 63, g = l >> 4, l15 = l & 15;

    // zero frag buffer + load coefficients
    {
      uint4 z = {0, 0, 0, 0};
#pragma unroll
      for (int i = 0; i < 4; i++) ((uint4*)t_frag)[tid + i * 256] = z;
    }
    if (tid < 128) {
      coef[0][tid] = dw[tid] + dw[256 + tid];
      coef[1][tid] = dw[128 + tid] + dw[384 + tid];
      coef[2][tid] = dw[512 + tid] + dw[768 + tid];
      coef[3][tid] = dw[640 + tid] + dw[896 + tid];
      coef[4][tid] = b1[tid];
      coef[5][tid] = b2[tid];
    }
    // reduce partials into registers (global reads only)
    const int r = tid >> 6;            // 0..3 (wave-per-row)
    const int c4 = (tid & 63) * 4;     // 4 cols per lane
    float rq[4] = {}, ra[4] = {};
#pragma unroll
    for (int p = 0; p < KSPLIT; p++) {
      uint2 q2 = *(const uint2*)(Rp + ((size_t)p * 4096 + b0 + r) * HD + c4);
      uint2 a2 = *(const uint2*)(Rp + ((size_t)p * 4096 + BATCH + b0 + r) * HD + c4);
      rq[0] += bf_lo(q2.x); rq[1] += bf_hi(q2.x);
      rq[2] += bf_lo(q2.y); rq[3] += bf_hi(q2.y);
      ra[0] += bf_lo(a2.x); ra[1] += bf_hi(a2.x);
      ra[2] += bf_lo(a2.y); ra[3] += bf_hi(a2.y);
    }
    uint2 tqv, mlv;
    {
      float d0 = rq[0] - ra[0], d1 = rq[1] - ra[1];
      float d2 = rq[2] - ra[2], d3 = rq[3] - ra[3];
      tqv.x = pack_bf2(d0 * d0, d1 * d1);
      tqv.y = pack_bf2(d2 * d2, d3 * d3);
      mlv.x = pack_bf2(rq[0] * ra[0], rq[1] * ra[1]);
      mlv.y = pack_bf2(rq[2] * ra[2], rq[3] * ra[3]);
    }
    __syncthreads();   // zero-fill complete
    {
      const int kcq = c4 >> 5, gq = (c4 >> 3) & 3, j0 = c4 & 7;
      *(uint2*)(t_frag + (kcq * 64 + gq * 16 + r) * 8 + j0) = tqv;
      *(uint2*)(t_frag + ((8 + kcq) * 64 + gq * 16 + r) * 8 + j0) = mlv;
    }
    __syncthreads();
    // tiny MFMA: wave wv -> channels ci = wv*6 .. wv*6+5
    {
      f32x4 acc[6] = {};
      const uint16_t* wB = Wm + ((size_t)(wv * 6) * 64 + l) * 8;
#pragma unroll 2
      for (int kc = 0; kc < 16; kc++) {
        bf16x8 af = *(const bf16x8*)(t_frag + (kc * 64 + l) * 8);
#pragma unroll
        for (int ci = 0; ci < 6; ci++) {
          bf16x8 w = *(const bf16x8*)(wB + (size_t)kc * 12288 + ci * 512);
          acc[ci] = __builtin_amdgcn_mfma_f32_16x16x32_bf16(af, w, acc[ci], 0, 0, 0);
        }
      }
      if (g == 0) {
#pragma unroll
        for (int ci = 0; ci < 6; ci++)
#pragma unroll
          for (int rg = 0; rg < 4; rg++)
            Cl[rg][wv * 96 + ci * 16 + l15] = acc[ci][rg];
      }
    }
    __syncthreads();
    // epilogue: wave r handles batch row b0+r; 64 lanes x 2 channels
    {
      const int c0 = (tid & 63) * 2;
      float s0 = 0.f, s1 = 0.f;
#pragma unroll
      for (int cc = 0; cc < 2; cc++) {
        const int c = c0 + cc;
        float d1 = Cl[r][c], d2a = Cl[r][128 + c], d2b = Cl[r][256 + c];
        float bb1 = coef[4][c], bb2 = coef[5][c];
        float e1 = fmaxf(0.f, fmaxf(bb1, d1 + bb1));          // max-pool conv1
        float e2 = fmaxf(0.f, fmaxf(d2a + bb2, d2b + bb2));   // max-pool conv2
        s0 += e1 * coef[0][c] + e2 * coef[1][c];
        s1 += e1 * coef[2][c] + e2 * coef[3][c];
      }
#pragma unroll
      for (int off = 32; off >= 1; off >>= 1) {
        s0 += __shfl_xor(s0, off);
        s1 += __shfl_xor(s1, off);
      }
      if ((tid & 63) == 0) {
        s0 += dbias[0]; s1 += dbias[1];
        float m = fmaxf(s0, s1);
        float lse = m + logf(expf(s0 - m) + expf(s1 - m));
        out[(b0 + r) * 2] = s0 - lse;
        out[(b0 + r) * 2 + 1] = s1 - lse;
      }
    }
  }
}

// ---------------------------------------------------------------- launch
extern "C" void kernel_launch(void* const* d_in, const int* in_sizes, int n_in,
                              void* d_out, int out_size, void* d_ws, size_t ws_size,
                              hipStream_t stream) {
  const float* emb = (const float*)d_in[0];
  const float* A   = (const float*)d_in[1];
  const float* k1  = (const float*)d_in[2];
  const float* b1  = (const float*)d_in[3];
  const float* k2  = (const float*)d_in[4];
  const float* b2  = (const float*)d_in[5];
  const float* dw  = (const float*)d_in[6];
  const float* dbi = (const float*)d_in[7];
  const int* bx = (const int*)d_in[8];
  const int* by = (const int*)d_in[9];
  float* out = (float*)d_out;
  char* ws = (char*)d_ws;
  // ws: [0,4M) Bm ; [4M,4.75M) Wm ; [8M,24M) Rp bf16 ; [24M,+256) barrier cnt
  uint16_t* Bm = (uint16_t*)ws;
  uint16_t* Wm = (uint16_t*)(ws + (4u << 20));
  uint16_t* Rp = (uint16_t*)(ws + (8u << 20));
  uint32_t* cnt = (uint32_t*)(ws + (24u << 20));

  hipMemsetAsync(cnt, 0, 256, stream);   // deterministic barrier counters
  k_all<<<NBLK, 256, 0, stream>>>(emb, A, k1, k2, b1, b2, dw, dbi,
                                  bx, by, out, Bm, Wm, Rp, cnt);
}

// Round 9
// 184.500 us; speedup vs baseline: 1.0882x; 1.0882x over previous
//
#include <hip/hip_runtime.h>
#include <stdint.h>
#include <math.h>

// Problem constants
#define NN 8192     // graph nodes == GEMM K
#define HD 256      // hidden dim == GEMM N
#define BATCH 2048
#define KSPLIT 8
#define KCH (NN / KSPLIT)   // 1024 K per kblk
#define NBLK 512            // grid size; 2 blocks/CU co-resident (capacity barrier)
#define NGRP 16
#define GRPSZ (NBLK / NGRP) // 32

typedef __attribute__((ext_vector_type(8))) short bf16x8;
typedef __attribute__((ext_vector_type(4))) float f32x4;

static __device__ __forceinline__ uint32_t pack_bf2(float x, float y) {
  union { float f; uint32_t u; } a, b; a.f = x; b.f = y;
  uint32_t ua = a.u + 0x7FFFu + ((a.u >> 16) & 1u);
  uint32_t ub = b.u + 0x7FFFu + ((b.u >> 16) & 1u);
  return (ua >> 16) | (ub & 0xFFFF0000u);
}
static __device__ __forceinline__ float bf_lo(uint32_t u) {
  return __uint_as_float(u << 16);
}
static __device__ __forceinline__ float bf_hi(uint32_t u) {
  return __uint_as_float(u & 0xFFFF0000u);
}

// Hierarchical device barrier. Per barrier idx: 16 group counters (128B apart,
// written by 32 blocks each, NEVER polled), 1 root counter (16 arrivals),
// 1 release flag (read-only broadcast; single release store wakes all).
// All 512 blocks are co-resident by capacity (launch_bounds (256,2) => 2/CU).
static __device__ __forceinline__ void grid_barrier(uint32_t* cnt, int idx) {
  uint32_t* base = cnt + idx * 1024;
  __syncthreads();
  if (threadIdx.x == 0) {
    uint32_t* grp  = base + (blockIdx.x >> 5) * 32;
    uint32_t* root = base + NGRP * 32;
    uint32_t* flag = base + NGRP * 32 + 32;
    __threadfence();
    uint32_t old = __hip_atomic_fetch_add(grp, 1u, __ATOMIC_ACQ_REL,
                                          __HIP_MEMORY_SCOPE_AGENT);
    if (old == GRPSZ - 1) {                      // last of my group
      uint32_t old2 = __hip_atomic_fetch_add(root, 1u, __ATOMIC_ACQ_REL,
                                             __HIP_MEMORY_SCOPE_AGENT);
      if (old2 == NGRP - 1)                      // last overall -> release
        __hip_atomic_store(flag, 1u, __ATOMIC_RELEASE,
                           __HIP_MEMORY_SCOPE_AGENT);
    }
    while (__hip_atomic_load(flag, __ATOMIC_ACQUIRE,
                             __HIP_MEMORY_SCOPE_AGENT) == 0u) {
      __builtin_amdgcn_s_sleep(2);
    }
    __threadfence();
  }
  __syncthreads();
}

// ================================================================ fused:
// phase A: prep Bm (frag-major bf16 of emb^T, XCD-local) + Wm (conv weights)
// phase B: split-K gather-GEMM  Rp[kblk][4096][256] bf16   (r6 body verbatim)
// phase C: reduce partials -> t -> tiny MFMA vs Wm -> log-softmax out
extern "C" __global__ __launch_bounds__(256, 2)
void k_all(const float* __restrict__ emb, const float* __restrict__ A,
           const float* __restrict__ k1, const float* __restrict__ k2,
           const float* __restrict__ b1, const float* __restrict__ b2,
           const float* __restrict__ dw, const float* __restrict__ dbias,
           const int* __restrict__ bx, const int* __restrict__ by,
           float* __restrict__ out,
           uint16_t* __restrict__ Bm, uint16_t* __restrict__ Wm,
           uint16_t* __restrict__ Rp, uint32_t* __restrict__ cnt) {
  __shared__ __align__(16) char smem[33024];
  const int tid = threadIdx.x;
  const int bid = blockIdx.x;

  // ======================= phase A: prep =======================
  if (bid < 256) {
    // kc chosen so this XCD (bid%8) produces the B-slice it will consume
    const int kc = (bid & 7) * 32 + (bid >> 3);
    float (*ts)[257] = (float(*)[257])smem;
#pragma unroll
    for (int i = 0; i < 32; i++)
      ts[i][tid] = emb[(size_t)(kc * 32 + i) * HD + tid];
    __syncthreads();
#pragma unroll
    for (int c = 0; c < 4; c++) {
      int e = c * 256 + tid;
      int ci = e >> 6, l = e & 63;
      int g = l >> 4, col = ci * 16 + (l & 15);
      uint4 v;
      v.x = pack_bf2(ts[g * 8 + 0][col], ts[g * 8 + 1][col]);
      v.y = pack_bf2(ts[g * 8 + 2][col], ts[g * 8 + 3][col]);
      v.z = pack_bf2(ts[g * 8 + 4][col], ts[g * 8 + 5][col]);
      v.w = pack_bf2(ts[g * 8 + 6][col], ts[g * 8 + 7][col]);
      ((uint4*)Bm)[(size_t)kc * 1024 + e] = v;
    }
  } else if (bid < 352) {
    const int c = (bid - 256) * 256 + tid;   // 0..24575
    const int lcl = c & 63;
    const int ci = (c >> 6) % 24;
    const int kc = c / (24 * 64);
    const int j = ci * 16 + (lcl & 15);
    const int k0 = kc * 32 + ((lcl >> 4) << 3);
    float f[8];
#pragma unroll
    for (int jj = 0; jj < 8; jj++) {
      int k = k0 + jj;
      f[jj] = (j < 128) ? k1[j * 514 + 1 + k]
            : (j < 256) ? k2[(j - 128) * 1028 + 515 + k]
                        : k2[(j - 256) * 1028 + 1 + k];
    }
    uint4 v;
    v.x = pack_bf2(f[0], f[1]); v.y = pack_bf2(f[2], f[3]);
    v.z = pack_bf2(f[4], f[5]); v.w = pack_bf2(f[6], f[7]);
    *(uint4*)(Wm + (size_t)c * 8) = v;
  }
  grid_barrier(cnt, 0);

  // ======================= phase B: gemm =======================
  {
    uint16_t* shb = (uint16_t*)smem;               // Af[2][4096] | Ct[64][256]
    const int kblk = bid & 7;                      // XCD = bid%8 == kblk
    const int mblk = bid >> 3;
    const int wv = tid >> 6, l = tid & 63, g = l >> 4, l15 = l & 15;

    // A gather: row = tid>>2 (4 threads per row, 16B each, contiguous)
    const int row = tid >> 2, q = tid & 3;
    const int gr = mblk * 64 + row;
    const int arow = (gr < BATCH) ? bx[gr] : by[gr - BATCH];
    const float* aSrc = A + (size_t)arow * NN + kblk * KCH + q * 4;
    int ldsO[4];
#pragma unroll
    for (int ii = 0; ii < 4; ii++) {
      int k0 = q * 4 + 16 * ii;
      int chunk = ((k0 >> 5) * 4 + (row >> 4)) * 64 + ((k0 >> 3) & 3) * 16 + (row & 15);
      ldsO[ii] = chunk * 16 + (k0 & 7) * 2;
    }
    const int ldsO0 = ldsO[0], ldsO1 = ldsO[1], ldsO2 = ldsO[2], ldsO3 = ldsO[3];
    const uint16_t* bWave = Bm + ((size_t)(kblk * 32 * 16 + wv * 4) * 64 + l) * 8;

    f32x4 acc[4][4] = {};
    float4 a0a, a0b, a0c, a0d, a1a, a1b, a1c, a1d, a2a, a2b, a2c, a2d;
    bf16x8 b0[2][4], b1[2][4];

#define ISSUE_A0(i) { const float* p_ = aSrc + (i) * 64; \
    a0a = *(const float4*)(p_);      a0b = *(const float4*)(p_ + 16); \
    a0c = *(const float4*)(p_ + 32); a0d = *(const float4*)(p_ + 48); }
#define ISSUE_A1(i) { const float* p_ = aSrc + (i) * 64; \
    a1a = *(const float4*)(p_);      a1b = *(const float4*)(p_ + 16); \
    a1c = *(const float4*)(p_ + 32); a1d = *(const float4*)(p_ + 48); }
#define ISSUE_A2(i) { const float* p_ = aSrc + (i) * 64; \
    a2a = *(const float4*)(p_);      a2b = *(const float4*)(p_ + 16); \
    a2c = *(const float4*)(p_ + 32); a2d = *(const float4*)(p_ + 48); }
#define ISSUE_B0(i) { \
    _Pragma("unroll") for (int kk = 0; kk < 2; kk++) \
    _Pragma("unroll") for (int cj = 0; cj < 4; cj++) \
      b0[kk][cj] = *(const bf16x8*)(bWave + ((i) * 2 + kk) * 8192 + cj * 512); }
#define ISSUE_B1(i) { \
    _Pragma("unroll") for (int kk = 0; kk < 2; kk++) \
    _Pragma("unroll") for (int cj = 0; cj < 4; cj++) \
      b1[kk][cj] = *(const bf16x8*)(bWave + ((i) * 2 + kk) * 8192 + cj * 512); }
#define PK1(va, off, buf) { uint2 v_; \
    v_.x = pack_bf2(va.x, va.y); v_.y = pack_bf2(va.z, va.w); \
    *(uint2*)((char*)shb + (buf) * 8192 + (off)) = v_; }
#define PACK_A0(buf) { PK1(a0a, ldsO0, buf); PK1(a0b, ldsO1, buf); \
                       PK1(a0c, ldsO2, buf); PK1(a0d, ldsO3, buf); }
#define PACK_A1(buf) { PK1(a1a, ldsO0, buf); PK1(a1b, ldsO1, buf); \
                       PK1(a1c, ldsO2, buf); PK1(a1d, ldsO3, buf); }
#define PACK_A2(buf) { PK1(a2a, ldsO0, buf); PK1(a2b, ldsO1, buf); \
                       PK1(a2c, ldsO2, buf); PK1(a2d, ldsO3, buf); }
#define COMPUTE(buf, bs) { \
    _Pragma("unroll") for (int kk = 0; kk < 2; kk++) { \
      _Pragma("unroll") for (int ri = 0; ri < 4; ri++) { \
        bf16x8 af = *(const bf16x8*)((char*)shb + (buf) * 8192 + \
                                     ((kk * 4 + ri) * 64 + l) * 16); \
        _Pragma("unroll") for (int cj = 0; cj < 4; cj++) \
          acc[ri][cj] = __builtin_amdgcn_mfma_f32_16x16x32_bf16( \
              af, bs[kk][cj], acc[ri][cj], 0, 0, 0); } } }
#define SYNC_ { asm volatile("s_waitcnt lgkmcnt(0)" ::: "memory"); \
    __builtin_amdgcn_s_barrier(); asm volatile("" ::: "memory"); }

    ISSUE_A0(0); ISSUE_A1(1); ISSUE_A2(2);
    ISSUE_B0(0); ISSUE_B1(1);
    PACK_A0(0);
    SYNC_;

#define SIX(base) \
  { COMPUTE(0, b0); ISSUE_A0((base) + 3); ISSUE_B0((base) + 2); PACK_A1(1); SYNC_; } \
  { COMPUTE(1, b1); ISSUE_A1((base) + 4); ISSUE_B1((base) + 3); PACK_A2(0); SYNC_; } \
  { COMPUTE(0, b0); ISSUE_A2((base) + 5); ISSUE_B0((base) + 4); PACK_A0(1); SYNC_; } \
  { COMPUTE(1, b1); ISSUE_A0((base) + 6); ISSUE_B1((base) + 5); PACK_A1(0); SYNC_; } \
  { COMPUTE(0, b0); ISSUE_A1((base) + 7); ISSUE_B0((base) + 6); PACK_A2(1); SYNC_; } \
  { COMPUTE(1, b1); ISSUE_A2((base) + 8); ISSUE_B1((base) + 7); PACK_A0(0); SYNC_; }

    SIX(0);
    SIX(6);
    { COMPUTE(0, b0); ISSUE_A0(15); ISSUE_B0(14); PACK_A1(1); SYNC_; }
    { COMPUTE(1, b1); ISSUE_B1(15); PACK_A2(0); SYNC_; }
    { COMPUTE(0, b0); PACK_A0(1); SYNC_; }
    { COMPUTE(1, b1); }
    SYNC_;                      // all LDS reads done; shb reusable as Ct

    uint16_t* Ct = shb;
#pragma unroll
    for (int ri = 0; ri < 4; ri++)
#pragma unroll
      for (int cj = 0; cj < 4; cj++)
#pragma unroll
        for (int r = 0; r < 4; r++) {
          float v = acc[ri][cj][r];
          float vn = __shfl_xor(v, 1);
          if ((l15 & 1) == 0) {
            int row16 = ri * 16 + g * 4 + r;
            int col = wv * 64 + cj * 16 + l15;
            *(uint32_t*)(Ct + row16 * 256 + col) = pack_bf2(v, vn);
          }
        }
    __syncthreads();
    {
      const int row2 = tid >> 2, cb = (tid & 3) * 64;
      const uint4* src = (const uint4*)(Ct + row2 * 256 + cb);
      uint16_t* dst = Rp + ((size_t)kblk * 4096 + mblk * 64 + row2) * HD + cb;
      uint4 v0 = src[0], v1 = src[1], v2 = src[2], v3 = src[3];
      ((uint4*)dst)[0] = v0; ((uint4*)dst)[1] = v1;
      ((uint4*)dst)[2] = v2; ((uint4*)dst)[3] = v3;
    }
#undef ISSUE_A0
#undef ISSUE_A1
#undef ISSUE_A2
#undef ISSUE_B0
#undef ISSUE_B1
#undef PK1
#undef PACK_A0
#undef PACK_A1
#undef PACK_A2
#undef COMPUTE
#undef SYNC_
#undef SIX
  }
  grid_barrier(cnt, 1);

  // ======================= phase C: tail =======================
  {
    uint16_t* t_frag = (uint16_t*)smem;                       // 16 KB
    float (*Cl)[388] = (float(*)[388])(smem + 16384);         // 4 rows used
    float (*coef)[128] = (float(*)[128])(smem + 22592);       // 3 KB
    const int b0 = bid * 4;
    const int wv = tid >> 6, l = tid & 63, g = l >> 4, l15 = l & 15;

    // zero frag buffer + load coefficients
    {
      uint4 z = {0, 0, 0, 0};
#pragma unroll
      for (int i = 0; i < 4; i++) ((uint4*)t_frag)[tid + i * 256] = z;
    }
    if (tid < 128) {
      coef[0][tid] = dw[tid] + dw[256 + tid];
      coef[1][tid] = dw[128 + tid] + dw[384 + tid];
      coef[2][tid] = dw[512 + tid] + dw[768 + tid];
      coef[3][tid] = dw[640 + tid] + dw[896 + tid];
      coef[4][tid] = b1[tid];
      coef[5][tid] = b2[tid];
    }
    // reduce partials into registers (global reads only)
    const int r = tid >> 6;            // 0..3 (wave-per-row)
    const int c4 = (tid & 63) * 4;     // 4 cols per lane
    float rq[4] = {}, ra[4] = {};
#pragma unroll
    for (int p = 0; p < KSPLIT; p++) {
      uint2 q2 = *(const uint2*)(Rp + ((size_t)p * 4096 + b0 + r) * HD + c4);
      uint2 a2 = *(const uint2*)(Rp + ((size_t)p * 4096 + BATCH + b0 + r) * HD + c4);
      rq[0] += bf_lo(q2.x); rq[1] += bf_hi(q2.x);
      rq[2] += bf_lo(q2.y); rq[3] += bf_hi(q2.y);
      ra[0] += bf_lo(a2.x); ra[1] += bf_hi(a2.x);
      ra[2] += bf_lo(a2.y); ra[3] += bf_hi(a2.y);
    }
    uint2 tqv, mlv;
    {
      float d0 = rq[0] - ra[0], d1 = rq[1] - ra[1];
      float d2 = rq[2] - ra[2], d3 = rq[3] - ra[3];
      tqv.x = pack_bf2(d0 * d0, d1 * d1);
      tqv.y = pack_bf2(d2 * d2, d3 * d3);
      mlv.x = pack_bf2(rq[0] * ra[0], rq[1] * ra[1]);
      mlv.y = pack_bf2(rq[2] * ra[2], rq[3] * ra[3]);
    }
    __syncthreads();   // zero-fill complete
    {
      const int kcq = c4 >> 5, gq = (c4 >> 3) & 3, j0 = c4 & 7;
      *(uint2*)(t_frag + (kcq * 64 + gq * 16 + r) * 8 + j0) = tqv;
      *(uint2*)(t_frag + ((8 + kcq) * 64 + gq * 16 + r) * 8 + j0) = mlv;
    }
    __syncthreads();
    // tiny MFMA: wave wv -> channels ci = wv*6 .. wv*6+5
    {
      f32x4 acc[6] = {};
      const uint16_t* wB = Wm + ((size_t)(wv * 6) * 64 + l) * 8;
#pragma unroll 2
      for (int kc = 0; kc < 16; kc++) {
        bf16x8 af = *(const bf16x8*)(t_frag + (kc * 64 + l) * 8);
#pragma unroll
        for (int ci = 0; ci < 6; ci++) {
          bf16x8 w = *(const bf16x8*)(wB + (size_t)kc * 12288 + ci * 512);
          acc[ci] = __builtin_amdgcn_mfma_f32_16x16x32_bf16(af, w, acc[ci], 0, 0, 0);
        }
      }
      if (g == 0) {
#pragma unroll
        for (int ci = 0; ci < 6; ci++)
#pragma unroll
          for (int rg = 0; rg < 4; rg++)
            Cl[rg][wv * 96 + ci * 16 + l15] = acc[ci][rg];
      }
    }
    __syncthreads();
    // epilogue: wave r handles batch row b0+r; 64 lanes x 2 channels
    {
      const int c0 = (tid & 63) * 2;
      float s0 = 0.f, s1 = 0.f;
#pragma unroll
      for (int cc = 0; cc < 2; cc++) {
        const int c = c0 + cc;
        float d1 = Cl[r][c], d2a = Cl[r][128 + c], d2b = Cl[r][256 + c];
        float bb1 = coef[4][c], bb2 = coef[5][c];
        float e1 = fmaxf(0.f, fmaxf(bb1, d1 + bb1));          // max-pool conv1
        float e2 = fmaxf(0.f, fmaxf(d2a + bb2, d2b + bb2));   // max-pool conv2
        s0 += e1 * coef[0][c] + e2 * coef[1][c];
        s1 += e1 * coef[2][c] + e2 * coef[3][c];
      }
#pragma unroll
      for (int off = 32; off >= 1; off >>= 1) {
        s0 += __shfl_xor(s0, off);
        s1 += __shfl_xor(s1, off);
      }
      if ((tid & 63) == 0) {
        s0 += dbias[0]; s1 += dbias[1];
        float m = fmaxf(s0, s1);
        float lse = m + logf(expf(s0 - m) + expf(s1 - m));
        out[(b0 + r) * 2] = s0 - lse;
        out[(b0 + r) * 2 + 1] = s1 - lse;
      }
    }
  }
}

// ---------------------------------------------------------------- launch
extern "C" void kernel_launch(void* const* d_in, const int* in_sizes, int n_in,
                              void* d_out, int out_size, void* d_ws, size_t ws_size,
                              hipStream_t stream) {
  const float* emb = (const float*)d_in[0];
  const float* A   = (const float*)d_in[1];
  const float* k1  = (const float*)d_in[2];
  const float* b1  = (const float*)d_in[3];
  const float* k2  = (const float*)d_in[4];
  const float* b2  = (const float*)d_in[5];
  const float* dw  = (const float*)d_in[6];
  const float* dbi = (const float*)d_in[7];
  const int* bx = (const int*)d_in[8];
  const int* by = (const int*)d_in[9];
  float* out = (float*)d_out;
  char* ws = (char*)d_ws;
  // ws: [0,4M) Bm ; [4M,4.75M) Wm ; [8M,24M) Rp bf16 ; [24M,+8K) barrier state
  uint16_t* Bm = (uint16_t*)ws;
  uint16_t* Wm = (uint16_t*)(ws + (4u << 20));
  uint16_t* Rp = (uint16_t*)(ws + (8u << 20));
  uint32_t* cnt = (uint32_t*)(ws + (24u << 20));

  hipMemsetAsync(cnt, 0, 8192, stream);   // deterministic barrier state
  k_all<<<NBLK, 256, 0, stream>>>(emb, A, k1, k2, b1, b2, dw, dbi,
                                  bx, by, out, Bm, Wm, Rp, cnt);
}

// Round 10
// 109.428 us; speedup vs baseline: 1.8347x; 1.6860x over previous
//
#include <hip/hip_runtime.h>
#include <stdint.h>
#include <math.h>

// Problem constants
#define NN 8192     // graph nodes == GEMM K
#define HD 256      // hidden dim == GEMM N
#define BATCH 2048
#define KSPLIT 8
#define KCH (NN / KSPLIT)   // 1024 K per kblk
#define NBLK 512            // grid size; 2 blocks/CU co-resident (capacity barrier)
#define NGRP 16
#define GRPSZ (NBLK / NGRP) // 32

typedef __attribute__((ext_vector_type(8))) short bf16x8;
typedef __attribute__((ext_vector_type(4))) float f32x4;

static __device__ __forceinline__ uint32_t pack_bf2(float x, float y) {
  union { float f; uint32_t u; } a, b; a.f = x; b.f = y;
  uint32_t ua = a.u + 0x7FFFu + ((a.u >> 16) & 1u);
  uint32_t ub = b.u + 0x7FFFu + ((b.u >> 16) & 1u);
  return (ua >> 16) | (ub & 0xFFFF0000u);
}
static __device__ __forceinline__ float bf_lo(uint32_t u) {
  return __uint_as_float(u << 16);
}
static __device__ __forceinline__ float bf_hi(uint32_t u) {
  return __uint_as_float(u & 0xFFFF0000u);
}

// Hierarchical device barrier with RELAXED polling.
// KEY FIX vs r9: agent-scope ACQUIRE loads emit an L2 invalidate (buffer_inv)
// on gfx950. Polling with ACQUIRE continuously invalidated every XCD's L2,
// destroying laggards' B-locality (the ~100us/barrier storm). Relaxed polls
// carry no invalidate; one ACQUIRE every 16 polls guarantees progress even if
// a relaxed load can be served stale; the single __threadfence after the spin
// performs the one acquire/invalidate actually required.
static __device__ __forceinline__ void grid_barrier(uint32_t* cnt, int idx) {
  uint32_t* base = cnt + idx * 1024;
  __syncthreads();
  if (threadIdx.x == 0) {
    uint32_t* grp  = base + (blockIdx.x >> 5) * 32;
    uint32_t* root = base + NGRP * 32;
    uint32_t* flag = base + NGRP * 32 + 32;
    __threadfence();                             // release my dirty data
    uint32_t old = __hip_atomic_fetch_add(grp, 1u, __ATOMIC_RELAXED,
                                          __HIP_MEMORY_SCOPE_AGENT);
    if (old == GRPSZ - 1) {                      // last of my group
      uint32_t old2 = __hip_atomic_fetch_add(root, 1u, __ATOMIC_RELAXED,
                                             __HIP_MEMORY_SCOPE_AGENT);
      if (old2 == NGRP - 1)                      // last overall -> release
        __hip_atomic_store(flag, 1u, __ATOMIC_RELEASE,
                           __HIP_MEMORY_SCOPE_AGENT);
    }
    int poll = 0;
    for (;;) {
      uint32_t f;
      if (((++poll) & 15) == 0)
        f = __hip_atomic_load(flag, __ATOMIC_ACQUIRE,
                              __HIP_MEMORY_SCOPE_AGENT);
      else
        f = __hip_atomic_load(flag, __ATOMIC_RELAXED,
                              __HIP_MEMORY_SCOPE_AGENT);
      if (f) break;
      __builtin_amdgcn_s_sleep(4);
    }
    __threadfence();                             // acquire others' data once
  }
  __syncthreads();
}

// ================================================================ fused:
// phase A: prep Bm (frag-major bf16 of emb^T, XCD-local) + Wm (conv weights)
// phase B: split-K gather-GEMM  Rp[kblk][4096][256] bf16   (r6 body verbatim)
// phase C: reduce partials -> t -> tiny MFMA vs Wm -> log-softmax out
extern "C" __global__ __launch_bounds__(256, 2)
void k_all(const float* __restrict__ emb, const float* __restrict__ A,
           const float* __restrict__ k1, const float* __restrict__ k2,
           const float* __restrict__ b1, const float* __restrict__ b2,
           const float* __restrict__ dw, const float* __restrict__ dbias,
           const int* __restrict__ bx, const int* __restrict__ by,
           float* __restrict__ out,
           uint16_t* __restrict__ Bm, uint16_t* __restrict__ Wm,
           uint16_t* __restrict__ Rp, uint32_t* __restrict__ cnt) {
  __shared__ __align__(16) char smem[33024];
  const int tid = threadIdx.x;
  const int bid = blockIdx.x;

  // ======================= phase A: prep =======================
  if (bid < 256) {
    // kc chosen so this XCD (bid%8) produces the B-slice it will consume
    const int kc = (bid & 7) * 32 + (bid >> 3);
    float (*ts)[257] = (float(*)[257])smem;
#pragma unroll
    for (int i = 0; i < 32; i++)
      ts[i][tid] = emb[(size_t)(kc * 32 + i) * HD + tid];
    __syncthreads();
#pragma unroll
    for (int c = 0; c < 4; c++) {
      int e = c * 256 + tid;
      int ci = e >> 6, l = e & 63;
      int g = l >> 4, col = ci * 16 + (l & 15);
      uint4 v;
      v.x = pack_bf2(ts[g * 8 + 0][col], ts[g * 8 + 1][col]);
      v.y = pack_bf2(ts[g * 8 + 2][col], ts[g * 8 + 3][col]);
      v.z = pack_bf2(ts[g * 8 + 4][col], ts[g * 8 + 5][col]);
      v.w = pack_bf2(ts[g * 8 + 6][col], ts[g * 8 + 7][col]);
      ((uint4*)Bm)[(size_t)kc * 1024 + e] = v;
    }
  } else if (bid < 352) {
    const int c = (bid - 256) * 256 + tid;   // 0..24575
    const int lcl = c & 63;
    const int ci = (c >> 6) % 24;
    const int kc = c / (24 * 64);
    const int j = ci * 16 + (lcl & 15);
    const int k0 = kc * 32 + ((lcl >> 4) << 3);
    float f[8];
#pragma unroll
    for (int jj = 0; jj < 8; jj++) {
      int k = k0 + jj;
      f[jj] = (j < 128) ? k1[j * 514 + 1 + k]
            : (j < 256) ? k2[(j - 128) * 1028 + 515 + k]
                        : k2[(j - 256) * 1028 + 1 + k];
    }
    uint4 v;
    v.x = pack_bf2(f[0], f[1]); v.y = pack_bf2(f[2], f[3]);
    v.z = pack_bf2(f[4], f[5]); v.w = pack_bf2(f[6], f[7]);
    *(uint4*)(Wm + (size_t)c * 8) = v;
  }
  grid_barrier(cnt, 0);

  // ======================= phase B: gemm =======================
  {
    uint16_t* shb = (uint16_t*)smem;               // Af[2][4096] | Ct[64][256]
    const int kblk = bid & 7;                      // XCD = bid%8 == kblk
    const int mblk = bid >> 3;
    const int wv = tid >> 6, l = tid & 63, g = l >> 4, l15 = l & 15;

    // A gather: row = tid>>2 (4 threads per row, 16B each, contiguous)
    const int row = tid >> 2, q = tid & 3;
    const int gr = mblk * 64 + row;
    const int arow = (gr < BATCH) ? bx[gr] : by[gr - BATCH];
    const float* aSrc = A + (size_t)arow * NN + kblk * KCH + q * 4;
    int ldsO[4];
#pragma unroll
    for (int ii = 0; ii < 4; ii++) {
      int k0 = q * 4 + 16 * ii;
      int chunk = ((k0 >> 5) * 4 + (row >> 4)) * 64 + ((k0 >> 3) & 3) * 16 + (row & 15);
      ldsO[ii] = chunk * 16 + (k0 & 7) * 2;
    }
    const int ldsO0 = ldsO[0], ldsO1 = ldsO[1], ldsO2 = ldsO[2], ldsO3 = ldsO[3];
    const uint16_t* bWave = Bm + ((size_t)(kblk * 32 * 16 + wv * 4) * 64 + l) * 8;

    f32x4 acc[4][4] = {};
    float4 a0a, a0b, a0c, a0d, a1a, a1b, a1c, a1d, a2a, a2b, a2c, a2d;
    bf16x8 b0[2][4], b1[2][4];

#define ISSUE_A0(i) { const float* p_ = aSrc + (i) * 64; \
    a0a = *(const float4*)(p_);      a0b = *(const float4*)(p_ + 16); \
    a0c = *(const float4*)(p_ + 32); a0d = *(const float4*)(p_ + 48); }
#define ISSUE_A1(i) { const float* p_ = aSrc + (i) * 64; \
    a1a = *(const float4*)(p_);      a1b = *(const float4*)(p_ + 16); \
    a1c = *(const float4*)(p_ + 32); a1d = *(const float4*)(p_ + 48); }
#define ISSUE_A2(i) { const float* p_ = aSrc + (i) * 64; \
    a2a = *(const float4*)(p_);      a2b = *(const float4*)(p_ + 16); \
    a2c = *(const float4*)(p_ + 32); a2d = *(const float4*)(p_ + 48); }
#define ISSUE_B0(i) { \
    _Pragma("unroll") for (int kk = 0; kk < 2; kk++) \
    _Pragma("unroll") for (int cj = 0; cj < 4; cj++) \
      b0[kk][cj] = *(const bf16x8*)(bWave + ((i) * 2 + kk) * 8192 + cj * 512); }
#define ISSUE_B1(i) { \
    _Pragma("unroll") for (int kk = 0; kk < 2; kk++) \
    _Pragma("unroll") for (int cj = 0; cj < 4; cj++) \
      b1[kk][cj] = *(const bf16x8*)(bWave + ((i) * 2 + kk) * 8192 + cj * 512); }
#define PK1(va, off, buf) { uint2 v_; \
    v_.x = pack_bf2(va.x, va.y); v_.y = pack_bf2(va.z, va.w); \
    *(uint2*)((char*)shb + (buf) * 8192 + (off)) = v_; }
#define PACK_A0(buf) { PK1(a0a, ldsO0, buf); PK1(a0b, ldsO1, buf); \
                       PK1(a0c, ldsO2, buf); PK1(a0d, ldsO3, buf); }
#define PACK_A1(buf) { PK1(a1a, ldsO0, buf); PK1(a1b, ldsO1, buf); \
                       PK1(a1c, ldsO2, buf); PK1(a1d, ldsO3, buf); }
#define PACK_A2(buf) { PK1(a2a, ldsO0, buf); PK1(a2b, ldsO1, buf); \
                       PK1(a2c, ldsO2, buf); PK1(a2d, ldsO3, buf); }
#define COMPUTE(buf, bs) { \
    _Pragma("unroll") for (int kk = 0; kk < 2; kk++) { \
      _Pragma("unroll") for (int ri = 0; ri < 4; ri++) { \
        bf16x8 af = *(const bf16x8*)((char*)shb + (buf) * 8192 + \
                                     ((kk * 4 + ri) * 64 + l) * 16); \
        _Pragma("unroll") for (int cj = 0; cj < 4; cj++) \
          acc[ri][cj] = __builtin_amdgcn_mfma_f32_16x16x32_bf16( \
              af, bs[kk][cj], acc[ri][cj], 0, 0, 0); } } }
#define SYNC_ { asm volatile("s_waitcnt lgkmcnt(0)" ::: "memory"); \
    __builtin_amdgcn_s_barrier(); asm volatile("" ::: "memory"); }

    ISSUE_A0(0); ISSUE_A1(1); ISSUE_A2(2);
    ISSUE_B0(0); ISSUE_B1(1);
    PACK_A0(0);
    SYNC_;

#define SIX(base) \
  { COMPUTE(0, b0); ISSUE_A0((base) + 3); ISSUE_B0((base) + 2); PACK_A1(1); SYNC_; } \
  { COMPUTE(1, b1); ISSUE_A1((base) + 4); ISSUE_B1((base) + 3); PACK_A2(0); SYNC_; } \
  { COMPUTE(0, b0); ISSUE_A2((base) + 5); ISSUE_B0((base) + 4); PACK_A0(1); SYNC_; } \
  { COMPUTE(1, b1); ISSUE_A0((base) + 6); ISSUE_B1((base) + 5); PACK_A1(0); SYNC_; } \
  { COMPUTE(0, b0); ISSUE_A1((base) + 7); ISSUE_B0((base) + 6); PACK_A2(1); SYNC_; } \
  { COMPUTE(1, b1); ISSUE_A2((base) + 8); ISSUE_B1((base) + 7); PACK_A0(0); SYNC_; }

    SIX(0);
    SIX(6);
    { COMPUTE(0, b0); ISSUE_A0(15); ISSUE_B0(14); PACK_A1(1); SYNC_; }
    { COMPUTE(1, b1); ISSUE_B1(15); PACK_A2(0); SYNC_; }
    { COMPUTE(0, b0); PACK_A0(1); SYNC_; }
    { COMPUTE(1, b1); }
    SYNC_;                      // all LDS reads done; shb reusable as Ct

    uint16_t* Ct = shb;
#pragma unroll
    for (int ri = 0; ri < 4; ri++)
#pragma unroll
      for (int cj = 0; cj < 4; cj++)
#pragma unroll
        for (int r = 0; r < 4; r++) {
          float v = acc[ri][cj][r];
          float vn = __shfl_xor(v, 1);
          if ((l15 & 1) == 0) {
            int row16 = ri * 16 + g * 4 + r;
            int col = wv * 64 + cj * 16 + l15;
            *(uint32_t*)(Ct + row16 * 256 + col) = pack_bf2(v, vn);
          }
        }
    __syncthreads();
    {
      const int row2 = tid >> 2, cb = (tid & 3) * 64;
      const uint4* src = (const uint4*)(Ct + row2 * 256 + cb);
      uint16_t* dst = Rp + ((size_t)kblk * 4096 + mblk * 64 + row2) * HD + cb;
      uint4 v0 = src[0], v1 = src[1], v2 = src[2], v3 = src[3];
      ((uint4*)dst)[0] = v0; ((uint4*)dst)[1] = v1;
      ((uint4*)dst)[2] = v2; ((uint4*)dst)[3] = v3;
    }
#undef ISSUE_A0
#undef ISSUE_A1
#undef ISSUE_A2
#undef ISSUE_B0
#undef ISSUE_B1
#undef PK1
#undef PACK_A0
#undef PACK_A1
#undef PACK_A2
#undef COMPUTE
#undef SYNC_
#undef SIX
  }
  grid_barrier(cnt, 1);

  // ======================= phase C: tail =======================
  {
    uint16_t* t_frag = (uint16_t*)smem;                       // 16 KB
    float (*Cl)[388] = (float(*)[388])(smem + 16384);         // 4 rows used
    float (*coef)[128] = (float(*)[128])(smem + 22592);       // 3 KB
    const int b0 = bid * 4;
    const int wv = tid >> 6, l = tid & 63, g = l >> 4, l15 = l & 15;

    // zero frag buffer + load coefficients
    {
      uint4 z = {0, 0, 0, 0};
#pragma unroll
      for (int i = 0; i < 4; i++) ((uint4*)t_frag)[tid + i * 256] = z;
    }
    if (tid < 128) {
      coef[0][tid] = dw[tid] + dw[256 + tid];
      coef[1][tid] = dw[128 + tid] + dw[384 + tid];
      coef[2][tid] = dw[512 + tid] + dw[768 + tid];
      coef[3][tid] = dw[640 + tid] + dw[896 + tid];
      coef[4][tid] = b1[tid];
      coef[5][tid] = b2[tid];
    }
    // reduce partials into registers (global reads only)
    const int r = tid >> 6;            // 0..3 (wave-per-row)
    const int c4 = (tid & 63) * 4;     // 4 cols per lane
    float rq[4] = {}, ra[4] = {};
#pragma unroll
    for (int p = 0; p < KSPLIT; p++) {
      uint2 q2 = *(const uint2*)(Rp + ((size_t)p * 4096 + b0 + r) * HD + c4);
      uint2 a2 = *(const uint2*)(Rp + ((size_t)p * 4096 + BATCH + b0 + r) * HD + c4);
      rq[0] += bf_lo(q2.x); rq[1] += bf_hi(q2.x);
      rq[2] += bf_lo(q2.y); rq[3] += bf_hi(q2.y);
      ra[0] += bf_lo(a2.x); ra[1] += bf_hi(a2.x);
      ra[2] += bf_lo(a2.y); ra[3] += bf_hi(a2.y);
    }
    uint2 tqv, mlv;
    {
      float d0 = rq[0] - ra[0], d1 = rq[1] - ra[1];
      float d2 = rq[2] - ra[2], d3 = rq[3] - ra[3];
      tqv.x = pack_bf2(d0 * d0, d1 * d1);
      tqv.y = pack_bf2(d2 * d2, d3 * d3);
      mlv.x = pack_bf2(rq[0] * ra[0], rq[1] * ra[1]);
      mlv.y = pack_bf2(rq[2] * ra[2], rq[3] * ra[3]);
    }
    __syncthreads();   // zero-fill complete
    {
      const int kcq = c4 >> 5, gq = (c4 >> 3) & 3, j0 = c4 & 7;
      *(uint2*)(t_frag + (kcq * 64 + gq * 16 + r) * 8 + j0) = tqv;
      *(uint2*)(t_frag + ((8 + kcq) * 64 + gq * 16 + r) * 8 + j0) = mlv;
    }
    __syncthreads();
    // tiny MFMA: wave wv -> channels ci = wv*6 .. wv*6+5
    {
      f32x4 acc[6] = {};
      const uint16_t* wB = Wm + ((size_t)(wv * 6) * 64 + l) * 8;
#pragma unroll 2
      for (int kc = 0; kc < 16; kc++) {
        bf16x8 af = *(const bf16x8*)(t_frag + (kc * 64 + l) * 8);
#pragma unroll
        for (int ci = 0; ci < 6; ci++) {
          bf16x8 w = *(const bf16x8*)(wB + (size_t)kc * 12288 + ci * 512);
          acc[ci] = __builtin_amdgcn_mfma_f32_16x16x32_bf16(af, w, acc[ci], 0, 0, 0);
        }
      }
      if (g == 0) {
#pragma unroll
        for (int ci = 0; ci < 6; ci++)
#pragma unroll
          for (int rg = 0; rg < 4; rg++)
            Cl[rg][wv * 96 + ci * 16 + l15] = acc[ci][rg];
      }
    }
    __syncthreads();
    // epilogue: wave r handles batch row b0+r; 64 lanes x 2 channels
    {
      const int c0 = (tid & 63) * 2;
      float s0 = 0.f, s1 = 0.f;
#pragma unroll
      for (int cc = 0; cc < 2; cc++) {
        const int c = c0 + cc;
        float d1 = Cl[r][c], d2a = Cl[r][128 + c], d2b = Cl[r][256 + c];
        float bb1 = coef[4][c], bb2 = coef[5][c];
        float e1 = fmaxf(0.f, fmaxf(bb1, d1 + bb1));          // max-pool conv1
        float e2 = fmaxf(0.f, fmaxf(d2a + bb2, d2b + bb2));   // max-pool conv2
        s0 += e1 * coef[0][c] + e2 * coef[1][c];
        s1 += e1 * coef[2][c] + e2 * coef[3][c];
      }
#pragma unroll
      for (int off = 32; off >= 1; off >>= 1) {
        s0 += __shfl_xor(s0, off);
        s1 += __shfl_xor(s1, off);
      }
      if ((tid & 63) == 0) {
        s0 += dbias[0]; s1 += dbias[1];
        float m = fmaxf(s0, s1);
        float lse = m + logf(expf(s0 - m) + expf(s1 - m));
        out[(b0 + r) * 2] = s0 - lse;
        out[(b0 + r) * 2 + 1] = s1 - lse;
      }
    }
  }
}

// ---------------------------------------------------------------- launch
extern "C" void kernel_launch(void* const* d_in, const int* in_sizes, int n_in,
                              void* d_out, int out_size, void* d_ws, size_t ws_size,
                              hipStream_t stream) {
  const float* emb = (const float*)d_in[0];
  const float* A   = (const float*)d_in[1];
  const float* k1  = (const float*)d_in[2];
  const float* b1  = (const float*)d_in[3];
  const float* k2  = (const float*)d_in[4];
  const float* b2  = (const float*)d_in[5];
  const float* dw  = (const float*)d_in[6];
  const float* dbi = (const float*)d_in[7];
  const int* bx = (const int*)d_in[8];
  const int* by = (const int*)d_in[9];
  float* out = (float*)d_out;
  char* ws = (char*)d_ws;
  // ws: [0,4M) Bm ; [4M,4.75M) Wm ; [8M,24M) Rp bf16 ; [24M,+8K) barrier state
  uint16_t* Bm = (uint16_t*)ws;
  uint16_t* Wm = (uint16_t*)(ws + (4u << 20));
  uint16_t* Rp = (uint16_t*)(ws + (8u << 20));
  uint32_t* cnt = (uint32_t*)(ws + (24u << 20));

  hipMemsetAsync(cnt, 0, 8192, stream);   // deterministic barrier state
  k_all<<<NBLK, 256, 0, stream>>>(emb, A, k1, k2, b1, b2, dw, dbi,
                                  bx, by, out, Bm, Wm, Rp, cnt);
}